// Round 1
// baseline (220.725 us; speedup 1.0000x reference)
//
#include <hip/hip_runtime.h>
#include <hip/hip_bf16.h>
#include <cmath>

#define B_   4
#define NT_  2048
#define G_   4096
#define DZ_  128

typedef __attribute__((ext_vector_type(8))) short bf16x8;
typedef __attribute__((ext_vector_type(4))) float f32x4;

__device__ __forceinline__ float softplus_f(float x) {
    return fmaxf(x, 0.0f) + log1pf(expf(-fabsf(x)));
}

// async 16B global -> LDS (lane i lands at ldst + 16*i; ldst wave-uniform)
__device__ __forceinline__ void gl2lds16(const void* gsrc, void* ldst) {
    __builtin_amdgcn_global_load_lds(
        (const __attribute__((address_space(1))) unsigned int*)gsrc,
        (__attribute__((address_space(3))) unsigned int*)ldst, 16, 0, 0);
}

// z_grid (B,G,DZ) fp32 -> Zt2 tiled bf16: Zt2[((b*128 + c)*128 + z)*32 + gi],
// c = g>>5, gi = g&31.  Each 8 KB chunk-tile is contiguous.  (unchanged)
__global__ __launch_bounds__(256, 1)
void transpose_z(const float* __restrict__ z, unsigned short* __restrict__ zt)
{
    __shared__ unsigned short tile[64][66];
    const int bx = blockIdx.x;                // 4b * 64gt * 2zt = 512
    const int zti = bx & 1;
    const int gt  = (bx >> 1) & 63;
    const int b   = bx >> 7;
    const int g0 = gt * 64, z0 = zti * 64;
    const int tid = threadIdx.x;
    const int zl = tid & 63, gl = tid >> 6;
    #pragma unroll
    for (int i = 0; i < 16; ++i) {
        const int g = gl + i * 4;
        const float v = z[(size_t)(b * G_ + g0 + g) * DZ_ + z0 + zl];
        unsigned int u = __float_as_uint(v);
        u = u + 0x7FFFu + ((u >> 16) & 1u);   // RNE to bf16
        tile[g][zl] = (unsigned short)(u >> 16);
    }
    __syncthreads();
    const int gp = (tid & 31) * 2, zi = tid >> 5;
    const int c  = (g0 + gp) >> 5, gi = gp & 31;
    #pragma unroll
    for (int i = 0; i < 8; ++i) {
        const int zz = zi + i * 8;
        const unsigned int lo = tile[gp][zz], hi = tile[gp + 1][zz];
        *(unsigned int*)(zt + ((size_t)(b * 128 + c) * 128 + z0 + zz) * 32 + gi)
            = lo | (hi << 16);
    }
}

// Block = (b, 32 t) x 128 z x 4096 g.  8 waves = 8-way kh g-split (512 g each).
// v2: Tt=32 via TWO A-frags per wave sharing every B ds_read / staged byte
//     -> Zt L2 traffic halves (512->256 MB).  Per-wave DOUBLE-BUFFERED private
//     LDS tiles (2 x 8 KB, 128 KB/block, 1 block/CU) with counted vmcnt(8):
//     stage(ch+2) stays in flight across the whole chunk, never a full drain.
// Grid 256 = 4b x 64tt, b = bx&3 -> one b per XCD (1 MB Zt slice L2-resident).
__global__ __launch_bounds__(512, 2)
void setconv_main(const float* __restrict__ xt,
                  const float* __restrict__ xg,
                  const float* __restrict__ lsp,
                  const unsigned short* __restrict__ Zt,
                  float* __restrict__ out)
{
    __shared__ __align__(16) unsigned short lds[65536];  // 128 KB: 8 waves x 2 x 8 KB

    const int bx = blockIdx.x;                // 256 blocks
    const int b  = bx & 3;                    // XCD x sees only b = x&3
    const int tt = bx >> 2;                   // 0..63
    const int tid  = threadIdx.x;
    const int w    = tid >> 6;                // = kh, 0..7
    const int lane = tid & 63;
    const int quad = lane >> 4;
    const int l15  = lane & 15;
    const int t0   = tt * 32;

    float c00, c01, c10, c11;
    {
        const float h = -0.72134752f;         // -0.5*log2(e)
        float ls;
        ls = 1e-5f + softplus_f(lsp[0]); c00 = h / (ls * ls);
        ls = 1e-5f + softplus_f(lsp[1]); c01 = h / (ls * ls);
        ls = 1e-5f + softplus_f(lsp[2]); c10 = h / (ls * ls);
        ls = 1e-5f + softplus_f(lsp[3]); c11 = h / (ls * ls);
    }

    // two A-frag row sets: rows l15 (tset 0) and 16+l15 (tset 1)
    const float xtA0 = xt[(size_t)(b * NT_ + t0 + l15) * 2 + 0];
    const float xtA1 = xt[(size_t)(b * NT_ + t0 + l15) * 2 + 1];
    const float xtB0 = xt[(size_t)(b * NT_ + t0 + 16 + l15) * 2 + 0];
    const float xtB1 = xt[(size_t)(b * NT_ + t0 + 16 + l15) * 2 + 1];

    f32x4 acc[2][2][8];                       // [tset][k][nt]
    #pragma unroll
    for (int ts = 0; ts < 2; ++ts)
        #pragma unroll
        for (int k = 0; k < 2; ++k)
            #pragma unroll
            for (int n = 0; n < 8; ++n) acc[ts][k][n] = (f32x4)0.0f;

    unsigned short* const buf0 = lds + w * 8192;   // 2 x 8 KB private slots
    unsigned short* const buf1 = buf0 + 4096;
    const float* xgq = xg + (size_t)(b * G_ + w * 512 + quad * 8) * 2;
    const unsigned short* zs = Zt + (size_t)(b * 128 + w * 16) * 4096 + lane * 8;

    // prologue: xv(0) FIRST (older than all DMAs -> its wait leaves stages in
    // flight), then stage(0)->buf0, stage(1)->buf1.
    float4 xv0 = *(const float4*)(xgq + 0);
    float4 xv1 = *(const float4*)(xgq + 4);
    float4 xv2 = *(const float4*)(xgq + 8);
    float4 xv3 = *(const float4*)(xgq + 12);
    #pragma unroll
    for (int i = 0; i < 8; ++i)
        gl2lds16(zs + i * 512, buf0 + i * 512);
    #pragma unroll
    for (int i = 0; i < 8; ++i)
        gl2lds16(zs + 4096 + i * 512, buf1 + i * 512);

    #pragma unroll
    for (int ch = 0; ch < 16; ++ch) {
        // ---- weights(ch) for BOTH row sets from xv (no fresh vm wait) ----
        float gx[8], gy[8];
        gx[0]=xv0.x; gy[0]=xv0.y; gx[1]=xv0.z; gy[1]=xv0.w;
        gx[2]=xv1.x; gy[2]=xv1.y; gx[3]=xv1.z; gy[3]=xv1.w;
        gx[4]=xv2.x; gy[4]=xv2.y; gx[5]=xv2.z; gy[5]=xv2.w;
        gx[6]=xv3.x; gy[6]=xv3.y; gx[7]=xv3.z; gy[7]=xv3.w;
        union { bf16x8 v; unsigned int u[4]; } aA0, aA1, aB0, aB1;
        {
            unsigned int w0b[8], w1b[8];
            #pragma unroll
            for (int j = 0; j < 8; ++j) {
                const float d0 = xtA0 - gx[j];
                const float d1 = xtA1 - gy[j];
                const float q0 = d0 * d0;
                const float q1 = d1 * d1;
                const float e0 = fmaf(q1, c10, q0 * c00);
                const float e1 = fmaf(q1, c11, q0 * c01);
                w0b[j] = __float_as_uint(__builtin_amdgcn_exp2f(e0));
                w1b[j] = __float_as_uint(__builtin_amdgcn_exp2f(e1));
            }
            #pragma unroll
            for (int h = 0; h < 4; ++h) {
                aA0.u[h] = __builtin_amdgcn_perm(w0b[2*h+1], w0b[2*h], 0x07060302u);
                aA1.u[h] = __builtin_amdgcn_perm(w1b[2*h+1], w1b[2*h], 0x07060302u);
            }
        }
        {
            unsigned int w0b[8], w1b[8];
            #pragma unroll
            for (int j = 0; j < 8; ++j) {
                const float d0 = xtB0 - gx[j];
                const float d1 = xtB1 - gy[j];
                const float q0 = d0 * d0;
                const float q1 = d1 * d1;
                const float e0 = fmaf(q1, c10, q0 * c00);
                const float e1 = fmaf(q1, c11, q0 * c01);
                w0b[j] = __float_as_uint(__builtin_amdgcn_exp2f(e0));
                w1b[j] = __float_as_uint(__builtin_amdgcn_exp2f(e1));
            }
            #pragma unroll
            for (int h = 0; h < 4; ++h) {
                aB0.u[h] = __builtin_amdgcn_perm(w0b[2*h+1], w0b[2*h], 0x07060302u);
                aB1.u[h] = __builtin_amdgcn_perm(w1b[2*h+1], w1b[2*h], 0x07060302u);
            }
        }

        // ---- counted drain: everything except S(ch+1) (8 newest).  S(ch) is
        // guaranteed complete; next-chunk staging stays in flight. ----
        __builtin_amdgcn_s_waitcnt(0x0F78);          // vmcnt(8)

        // ---- xv(ch+1) prefetch (issued after wait: never force-drained) ----
        if (ch < 15) {
            const float* xp = xgq + (ch + 1) * 64;
            xv0 = *(const float4*)(xp + 0);
            xv1 = *(const float4*)(xp + 4);
            xv2 = *(const float4*)(xp + 8);
            xv3 = *(const float4*)(xp + 12);
        }

        // ---- consume tile(ch): 8 ds_read_b128 shared by 4 MFMAs each ----
        const unsigned short* tile = (ch & 1) ? buf1 : buf0;
        #pragma unroll
        for (int nt = 0; nt < 8; ++nt) {
            const bf16x8 bz = *(const bf16x8*)(tile + nt * 512 + l15 * 32 + quad * 8);
            acc[0][0][nt] = __builtin_amdgcn_mfma_f32_16x16x32_bf16(aA0.v, bz, acc[0][0][nt], 0, 0, 0);
            acc[0][1][nt] = __builtin_amdgcn_mfma_f32_16x16x32_bf16(aA1.v, bz, acc[0][1][nt], 0, 0, 0);
            acc[1][0][nt] = __builtin_amdgcn_mfma_f32_16x16x32_bf16(aB0.v, bz, acc[1][0][nt], 0, 0, 0);
            acc[1][1][nt] = __builtin_amdgcn_mfma_f32_16x16x32_bf16(aB1.v, bz, acc[1][1][nt], 0, 0, 0);
        }

        // ---- stage(ch+2) into the just-consumed slot (MFMAs' lgkm waits
        // guarantee the ds_reads completed before these DMAs can land) ----
        if (ch < 14) {
            const unsigned short* zc = zs + (size_t)(ch + 2) * 4096;
            unsigned short* dst = (ch & 1) ? buf1 : buf0;
            #pragma unroll
            for (int i = 0; i < 8; ++i)
                gl2lds16(zc + i * 512, dst + i * 512);
        }
    }

    // ---- 3-round k-reduction over the 8 kh-waves (aliases wave tiles) ----
    float* const red = (float*)lds;
    #define RED_W(slot) { \
        float* bp = &red[(slot) * 8192 + lane * 4]; \
        _Pragma("unroll") \
        for (int ts = 0; ts < 2; ++ts) \
            _Pragma("unroll") \
            for (int k = 0; k < 2; ++k) \
                _Pragma("unroll") \
                for (int n = 0; n < 8; ++n) \
                    *(f32x4*)(bp + (ts * 16 + k * 8 + n) * 256) = acc[ts][k][n]; }
    #define RED_A(slot) { \
        const float* bp = &red[(slot) * 8192 + lane * 4]; \
        _Pragma("unroll") \
        for (int ts = 0; ts < 2; ++ts) \
            _Pragma("unroll") \
            for (int k = 0; k < 2; ++k) \
                _Pragma("unroll") \
                for (int n = 0; n < 8; ++n) \
                    acc[ts][k][n] += *(const f32x4*)(bp + (ts * 16 + k * 8 + n) * 256); }
    #define RED_W_T(slot, ts) { \
        float* bp = &red[(slot) * 8192 + lane * 4]; \
        _Pragma("unroll") \
        for (int k = 0; k < 2; ++k) \
            _Pragma("unroll") \
            for (int n = 0; n < 8; ++n) \
                *(f32x4*)(bp + (k * 8 + n) * 256) = acc[ts][k][n]; }
    #define RED_A_T(slot, ts) { \
        const float* bp = &red[(slot) * 8192 + lane * 4]; \
        _Pragma("unroll") \
        for (int k = 0; k < 2; ++k) \
            _Pragma("unroll") \
            for (int n = 0; n < 8; ++n) \
                acc[ts][k][n] += *(const f32x4*)(bp + (k * 8 + n) * 256); }

    __syncthreads();
    if (w >= 4) RED_W(w - 4);
    __syncthreads();
    if (w < 4) RED_A(w);
    if (w == 2 || w == 3) RED_W(w);
    __syncthreads();
    if (w < 2) RED_A(w + 2);
    // final round split by tset: w1 hands tset0 to w0, w0 hands tset1 to w1
    if (w == 1) RED_W_T(3, 0);
    if (w == 0) RED_W_T(2, 1);
    __syncthreads();
    if (w < 2) {
        if (w == 0) { RED_A_T(3, 0); } else { RED_A_T(2, 1); }
        const int ts = w;
        const int tr = t0 + ts * 16 + quad * 4;
        #pragma unroll
        for (int nt = 0; nt < 8; ++nt) {
            float* ob = out + (size_t)(b * NT_ + tr) * (DZ_ * 2) + (nt * 16 + l15) * 2;
            #pragma unroll
            for (int r = 0; r < 4; ++r)
                *(float2*)(ob + (size_t)r * (DZ_ * 2)) =
                    make_float2(acc[ts][0][nt][r], acc[ts][1][nt][r]);
        }
    }
    #undef RED_W
    #undef RED_A
    #undef RED_W_T
    #undef RED_A_T
}

extern "C" void kernel_launch(void* const* d_in, const int* in_sizes, int n_in,
                              void* d_out, int out_size, void* d_ws, size_t ws_size,
                              hipStream_t stream)
{
    const float* x_grid = (const float*)d_in[0];   // (4,64,64,2)
    const float* z_grid = (const float*)d_in[1];   // (4,64,64,128)
    const float* xt     = (const float*)d_in[2];   // (4,2048,2)
    const float* lsp    = (const float*)d_in[3];   // (2,2)
    float* out = (float*)d_out;                    // (4,2048,256) fp32
    unsigned short* Zt = (unsigned short*)d_ws;    // tiled, 4 MB

    hipLaunchKernelGGL(transpose_z, dim3(512), dim3(256), 0, stream, z_grid, Zt);
    hipLaunchKernelGGL(setconv_main, dim3(256), dim3(512), 0, stream,
                       xt, x_grid, lsp, Zt, out);
}

// Round 2
// 121.487 us; speedup vs baseline: 1.8169x; 1.8169x over previous
//
#include <hip/hip_runtime.h>
#include <hip/hip_bf16.h>
#include <cmath>

#define B_   4
#define NT_  2048
#define G_   4096
#define DZ_  128

typedef __attribute__((ext_vector_type(8))) short bf16x8;
typedef __attribute__((ext_vector_type(4))) float f32x4;

__device__ __forceinline__ float softplus_f(float x) {
    return fmaxf(x, 0.0f) + log1pf(expf(-fabsf(x)));
}

// async 16B global -> LDS (lane i lands at ldst + 16*i; ldst wave-uniform)
__device__ __forceinline__ void gl2lds16(const void* gsrc, void* ldst) {
    __builtin_amdgcn_global_load_lds(
        (const __attribute__((address_space(1))) unsigned int*)gsrc,
        (__attribute__((address_space(3))) unsigned int*)ldst, 16, 0, 0);
}

// z_grid (B,G,DZ) fp32 -> Zt2 tiled bf16: Zt2[((b*128 + c)*128 + z)*32 + gi],
// c = g>>5, gi = g&31.  Each 8 KB chunk-tile is contiguous.  (unchanged)
__global__ __launch_bounds__(256, 1)
void transpose_z(const float* __restrict__ z, unsigned short* __restrict__ zt)
{
    __shared__ unsigned short tile[64][66];
    const int bx = blockIdx.x;                // 4b * 64gt * 2zt = 512
    const int zti = bx & 1;
    const int gt  = (bx >> 1) & 63;
    const int b   = bx >> 7;
    const int g0 = gt * 64, z0 = zti * 64;
    const int tid = threadIdx.x;
    const int zl = tid & 63, gl = tid >> 6;
    #pragma unroll
    for (int i = 0; i < 16; ++i) {
        const int g = gl + i * 4;
        const float v = z[(size_t)(b * G_ + g0 + g) * DZ_ + z0 + zl];
        unsigned int u = __float_as_uint(v);
        u = u + 0x7FFFu + ((u >> 16) & 1u);   // RNE to bf16
        tile[g][zl] = (unsigned short)(u >> 16);
    }
    __syncthreads();
    const int gp = (tid & 31) * 2, zi = tid >> 5;
    const int c  = (g0 + gp) >> 5, gi = gp & 31;
    #pragma unroll
    for (int i = 0; i < 8; ++i) {
        const int zz = zi + i * 8;
        const unsigned int lo = tile[gp][zz], hi = tile[gp + 1][zz];
        *(unsigned int*)(zt + ((size_t)(b * 128 + c) * 128 + z0 + zz) * 32 + gi)
            = lo | (hi << 16);
    }
}

// v3: Block = 256 thr (4 waves), (b, 32 t) x 128 z x 4096 g.
// 4 waves = 4-way g-split (1024 g / 32 chunks each).  Tt=32 via TWO A-frags
// per wave sharing every staged byte (Zt L2 traffic 256 MB total).
// KEY FIX vs v2: 4-wave block -> HW reg cap ~512/wave (vs 256 for 8-wave),
// so acc[2][2][8] (128 regs) CANNOT spill to scratch (v2 spilled 1.07 GB).
// Private per-wave double-buffered LDS tiles (2 x 8 KB), counted vmcnt(8):
// stage(ch+2) issued at end of chunk ch -> ~1.5 chunks of DMA lead time.
__global__ __launch_bounds__(256, 1)
void setconv_main(const float* __restrict__ xt,
                  const float* __restrict__ xg,
                  const float* __restrict__ lsp,
                  const unsigned short* __restrict__ Zt,
                  float* __restrict__ out)
{
    __shared__ __align__(16) unsigned short lds[32768];  // 64 KB: 4 waves x 2 x 8 KB

    const int bx = blockIdx.x;                // 256 blocks = 4b x 64tt
    const int b  = bx & 3;                    // XCD pinning: same b -> 2 XCDs
    const int tt = bx >> 2;                   // 0..63
    const int tid  = threadIdx.x;
    const int w    = tid >> 6;                // 0..3: g-split
    const int lane = tid & 63;
    const int quad = lane >> 4;
    const int l15  = lane & 15;
    const int t0   = tt * 32;

    float c00, c01, c10, c11;
    {
        const float h = -0.72134752f;         // -0.5*log2(e)
        float ls;
        ls = 1e-5f + softplus_f(lsp[0]); c00 = h / (ls * ls);
        ls = 1e-5f + softplus_f(lsp[1]); c01 = h / (ls * ls);
        ls = 1e-5f + softplus_f(lsp[2]); c10 = h / (ls * ls);
        ls = 1e-5f + softplus_f(lsp[3]); c11 = h / (ls * ls);
    }

    // two A-frag row sets: rows l15 (tset 0) and 16+l15 (tset 1)
    const float xtA0 = xt[(size_t)(b * NT_ + t0 + l15) * 2 + 0];
    const float xtA1 = xt[(size_t)(b * NT_ + t0 + l15) * 2 + 1];
    const float xtB0 = xt[(size_t)(b * NT_ + t0 + 16 + l15) * 2 + 0];
    const float xtB1 = xt[(size_t)(b * NT_ + t0 + 16 + l15) * 2 + 1];

    f32x4 acc[2][2][8];                       // [tset][k][nt] = 128 regs
    #pragma unroll
    for (int ts = 0; ts < 2; ++ts)
        #pragma unroll
        for (int k = 0; k < 2; ++k)
            #pragma unroll
            for (int n = 0; n < 8; ++n) acc[ts][k][n] = (f32x4)0.0f;

    unsigned short* const buf0 = lds + w * 8192;   // 2 x 8 KB private slots
    unsigned short* const buf1 = buf0 + 4096;
    const float* xgq = xg + (size_t)(b * G_ + w * 1024 + quad * 8) * 2;
    const unsigned short* zs = Zt + (size_t)(b * 128 + w * 32) * 4096 + lane * 8;

    // prologue: xv(0) FIRST (older than all DMAs), then stage(0), stage(1)
    float4 xv0 = *(const float4*)(xgq + 0);
    float4 xv1 = *(const float4*)(xgq + 4);
    float4 xv2 = *(const float4*)(xgq + 8);
    float4 xv3 = *(const float4*)(xgq + 12);
    #pragma unroll
    for (int i = 0; i < 8; ++i)
        gl2lds16(zs + i * 512, buf0 + i * 512);
    #pragma unroll
    for (int i = 0; i < 8; ++i)
        gl2lds16(zs + 4096 + i * 512, buf1 + i * 512);

    // Per-chunk body.  Correctness of the DMA/ds_read interleave: the MFMAs'
    // auto-inserted lgkmcnt waits complete all tile ds_reads before the
    // stage(ch+2) DMAs into the same slot are issued.
    #define CHUNK_BODY(CH, TILE)                                               \
    {                                                                          \
        const int ch_ = (CH);                                                  \
        float gx[8], gy[8];                                                    \
        gx[0]=xv0.x; gy[0]=xv0.y; gx[1]=xv0.z; gy[1]=xv0.w;                    \
        gx[2]=xv1.x; gy[2]=xv1.y; gx[3]=xv1.z; gy[3]=xv1.w;                    \
        gx[4]=xv2.x; gy[4]=xv2.y; gx[5]=xv2.z; gy[5]=xv2.w;                    \
        gx[6]=xv3.x; gy[6]=xv3.y; gx[7]=xv3.z; gy[7]=xv3.w;                    \
        union { bf16x8 v; unsigned int u[4]; } aA0, aA1, aB0, aB1;             \
        {                                                                      \
            unsigned int w0b[8], w1b[8];                                       \
            _Pragma("unroll")                                                  \
            for (int j = 0; j < 8; ++j) {                                      \
                const float d0 = xtA0 - gx[j];                                 \
                const float d1 = xtA1 - gy[j];                                 \
                const float q0 = d0 * d0;                                      \
                const float q1 = d1 * d1;                                      \
                const float e0 = fmaf(q1, c10, q0 * c00);                      \
                const float e1 = fmaf(q1, c11, q0 * c01);                      \
                w0b[j] = __float_as_uint(__builtin_amdgcn_exp2f(e0));          \
                w1b[j] = __float_as_uint(__builtin_amdgcn_exp2f(e1));          \
            }                                                                  \
            _Pragma("unroll")                                                  \
            for (int h = 0; h < 4; ++h) {                                      \
                aA0.u[h] = __builtin_amdgcn_perm(w0b[2*h+1], w0b[2*h], 0x07060302u); \
                aA1.u[h] = __builtin_amdgcn_perm(w1b[2*h+1], w1b[2*h], 0x07060302u); \
            }                                                                  \
        }                                                                      \
        {                                                                      \
            unsigned int w0b[8], w1b[8];                                       \
            _Pragma("unroll")                                                  \
            for (int j = 0; j < 8; ++j) {                                      \
                const float d0 = xtB0 - gx[j];                                 \
                const float d1 = xtB1 - gy[j];                                 \
                const float q0 = d0 * d0;                                      \
                const float q1 = d1 * d1;                                      \
                const float e0 = fmaf(q1, c10, q0 * c00);                      \
                const float e1 = fmaf(q1, c11, q0 * c01);                      \
                w0b[j] = __float_as_uint(__builtin_amdgcn_exp2f(e0));          \
                w1b[j] = __float_as_uint(__builtin_amdgcn_exp2f(e1));          \
            }                                                                  \
            _Pragma("unroll")                                                  \
            for (int h = 0; h < 4; ++h) {                                      \
                aB0.u[h] = __builtin_amdgcn_perm(w0b[2*h+1], w0b[2*h], 0x07060302u); \
                aB1.u[h] = __builtin_amdgcn_perm(w1b[2*h+1], w1b[2*h], 0x07060302u); \
            }                                                                  \
        }                                                                      \
        /* counted drain: leaves next-chunk staging in flight */               \
        __builtin_amdgcn_s_waitcnt(0x0F78);          /* vmcnt(8) */            \
        if (ch_ < 31) {                                                        \
            const float* xp = xgq + (ch_ + 1) * 64;                            \
            xv0 = *(const float4*)(xp + 0);                                    \
            xv1 = *(const float4*)(xp + 4);                                    \
            xv2 = *(const float4*)(xp + 8);                                    \
            xv3 = *(const float4*)(xp + 12);                                   \
        }                                                                      \
        _Pragma("unroll")                                                      \
        for (int nt = 0; nt < 8; ++nt) {                                       \
            const bf16x8 bz = *(const bf16x8*)((TILE) + nt * 512 + l15 * 32 + quad * 8); \
            acc[0][0][nt] = __builtin_amdgcn_mfma_f32_16x16x32_bf16(aA0.v, bz, acc[0][0][nt], 0, 0, 0); \
            acc[0][1][nt] = __builtin_amdgcn_mfma_f32_16x16x32_bf16(aA1.v, bz, acc[0][1][nt], 0, 0, 0); \
            acc[1][0][nt] = __builtin_amdgcn_mfma_f32_16x16x32_bf16(aB0.v, bz, acc[1][0][nt], 0, 0, 0); \
            acc[1][1][nt] = __builtin_amdgcn_mfma_f32_16x16x32_bf16(aB1.v, bz, acc[1][1][nt], 0, 0, 0); \
        }                                                                      \
        if (ch_ < 30) {                                                        \
            const unsigned short* zc = zs + (size_t)(ch_ + 2) * 4096;          \
            _Pragma("unroll")                                                  \
            for (int i = 0; i < 8; ++i)                                        \
                gl2lds16(zc + i * 512, (TILE) + i * 512);                      \
        }                                                                      \
    }

    for (int p = 0; p < 16; ++p) {
        CHUNK_BODY(2 * p,     buf0);
        CHUNK_BODY(2 * p + 1, buf1);
    }
    #undef CHUNK_BODY

    // ---- 2-round g-split reduction over the 4 waves (aliases wave tiles) ----
    float* const red = (float*)lds;           // slot s: 32 KB at s*8192 floats
    #define RED_W(slot) { \
        float* bp = &red[(slot) * 8192 + lane * 4]; \
        _Pragma("unroll") \
        for (int ts = 0; ts < 2; ++ts) \
            _Pragma("unroll") \
            for (int k = 0; k < 2; ++k) \
                _Pragma("unroll") \
                for (int n = 0; n < 8; ++n) \
                    *(f32x4*)(bp + (ts * 16 + k * 8 + n) * 256) = acc[ts][k][n]; }
    #define RED_A(slot) { \
        const float* bp = &red[(slot) * 8192 + lane * 4]; \
        _Pragma("unroll") \
        for (int ts = 0; ts < 2; ++ts) \
            _Pragma("unroll") \
            for (int k = 0; k < 2; ++k) \
                _Pragma("unroll") \
                for (int n = 0; n < 8; ++n) \
                    acc[ts][k][n] += *(const f32x4*)(bp + (ts * 16 + k * 8 + n) * 256); }
    #define RED_W_T(slot, ts) { \
        float* bp = &red[(slot) * 8192 + lane * 4]; \
        _Pragma("unroll") \
        for (int k = 0; k < 2; ++k) \
            _Pragma("unroll") \
            for (int n = 0; n < 8; ++n) \
                *(f32x4*)(bp + (k * 8 + n) * 256) = acc[ts][k][n]; }
    #define RED_A_T(slot, ts) { \
        const float* bp = &red[(slot) * 8192 + lane * 4]; \
        _Pragma("unroll") \
        for (int k = 0; k < 2; ++k) \
            _Pragma("unroll") \
            for (int n = 0; n < 8; ++n) \
                acc[ts][k][n] += *(const f32x4*)(bp + (k * 8 + n) * 256); }

    __syncthreads();
    if (w >= 2) RED_W(w - 2);                 // w2 -> slot0, w3 -> slot1
    __syncthreads();
    if (w < 2) RED_A(w);                      // w0 += slot0, w1 += slot1
    // final round split by tset: w1 hands tset0 to w0, w0 hands tset1 to w1
    if (w == 1) RED_W_T(0, 0);
    if (w == 0) RED_W_T(1, 1);
    __syncthreads();
    if (w < 2) {
        if (w == 0) { RED_A_T(0, 0); } else { RED_A_T(1, 1); }
        const int ts = w;
        const int tr = t0 + ts * 16 + quad * 4;
        #pragma unroll
        for (int nt = 0; nt < 8; ++nt) {
            float* ob = out + (size_t)(b * NT_ + tr) * (DZ_ * 2) + (nt * 16 + l15) * 2;
            #pragma unroll
            for (int r = 0; r < 4; ++r)
                *(float2*)(ob + (size_t)r * (DZ_ * 2)) =
                    make_float2(acc[ts][0][nt][r], acc[ts][1][nt][r]);
        }
    }
    #undef RED_W
    #undef RED_A
    #undef RED_W_T
    #undef RED_A_T
}

extern "C" void kernel_launch(void* const* d_in, const int* in_sizes, int n_in,
                              void* d_out, int out_size, void* d_ws, size_t ws_size,
                              hipStream_t stream)
{
    const float* x_grid = (const float*)d_in[0];   // (4,64,64,2)
    const float* z_grid = (const float*)d_in[1];   // (4,64,64,128)
    const float* xt     = (const float*)d_in[2];   // (4,2048,2)
    const float* lsp    = (const float*)d_in[3];   // (2,2)
    float* out = (float*)d_out;                    // (4,2048,256) fp32
    unsigned short* Zt = (unsigned short*)d_ws;    // tiled, 4 MB

    hipLaunchKernelGGL(transpose_z, dim3(512), dim3(256), 0, stream, z_grid, Zt);
    hipLaunchKernelGGL(setconv_main, dim3(256), dim3(256), 0, stream,
                       xt, x_grid, lsp, Zt, out);
}

// Round 3
// 114.470 us; speedup vs baseline: 1.9282x; 1.0613x over previous
//
#include <hip/hip_runtime.h>
#include <hip/hip_bf16.h>
#include <cmath>

#define B_   4
#define NT_  2048
#define G_   4096
#define DZ_  128

typedef __attribute__((ext_vector_type(8))) short bf16x8;
typedef __attribute__((ext_vector_type(4))) float f32x4;

__device__ __forceinline__ float softplus_f(float x) {
    return fmaxf(x, 0.0f) + log1pf(expf(-fabsf(x)));
}

// async 16B global -> LDS (lane i lands at ldst + 16*i; ldst wave-uniform)
__device__ __forceinline__ void gl2lds16(const void* gsrc, void* ldst) {
    __builtin_amdgcn_global_load_lds(
        (const __attribute__((address_space(1))) unsigned int*)gsrc,
        (__attribute__((address_space(3))) unsigned int*)ldst, 16, 0, 0);
}

// z_grid (B,G,DZ) fp32 -> Zt2 tiled bf16: Zt2[((b*128 + c)*128 + z)*32 + gi],
// c = g>>5, gi = g&31.  Each 8 KB chunk-tile is contiguous.  (unchanged)
__global__ __launch_bounds__(256, 1)
void transpose_z(const float* __restrict__ z, unsigned short* __restrict__ zt)
{
    __shared__ unsigned short tile[64][66];
    const int bx = blockIdx.x;                // 4b * 64gt * 2zt = 512
    const int zti = bx & 1;
    const int gt  = (bx >> 1) & 63;
    const int b   = bx >> 7;
    const int g0 = gt * 64, z0 = zti * 64;
    const int tid = threadIdx.x;
    const int zl = tid & 63, gl = tid >> 6;
    #pragma unroll
    for (int i = 0; i < 16; ++i) {
        const int g = gl + i * 4;
        const float v = z[(size_t)(b * G_ + g0 + g) * DZ_ + z0 + zl];
        unsigned int u = __float_as_uint(v);
        u = u + 0x7FFFu + ((u >> 16) & 1u);   // RNE to bf16
        tile[g][zl] = (unsigned short)(u >> 16);
    }
    __syncthreads();
    const int gp = (tid & 31) * 2, zi = tid >> 5;
    const int c  = (g0 + gp) >> 5, gi = gp & 31;
    #pragma unroll
    for (int i = 0; i < 8; ++i) {
        const int zz = zi + i * 8;
        const unsigned int lo = tile[gp][zz], hi = tile[gp + 1][zz];
        *(unsigned int*)(zt + ((size_t)(b * 128 + c) * 128 + z0 + zz) * 32 + gi)
            = lo | (hi << 16);
    }
}

// v4: Block = 512 thr (8 waves), (b, 32 t) x 128 z x 4096 g.
// Waves: w = ts*4 + p.  p = g-group (4-way g-split, 1024 g / 32 chunks),
// ts = t-set (rows t0+ts*16 .. +15).  The two waves of pair (p) SHARE one
// double-buffered staged tile (2 x 8 KB), each staging half and each
// consuming all of it -> Zt L2 traffic halves vs v1 (256 MB total) while
// acc/wave stays 64 regs (v1's proven no-spill regime; v2/v3 spilled).
// Cross-wave sharing via verified 8-phase primitives: raw s_barrier +
// counted vmcnt(8) (stage DMAs stay in flight across barriers).
__global__ __launch_bounds__(512, 2)
void setconv_main(const float* __restrict__ xt,
                  const float* __restrict__ xg,
                  const float* __restrict__ lsp,
                  const unsigned short* __restrict__ Zt,
                  float* __restrict__ out)
{
    __shared__ __align__(16) unsigned short lds[32768];  // 64 KB: 4 pairs x 2 x 8 KB

    const int bx = blockIdx.x;                // 256 blocks = 4b x 64tt
    const int b  = bx & 3;                    // XCD x sees only b = x&3
    const int tt = bx >> 2;                   // 0..63
    const int tid  = threadIdx.x;
    const int w    = tid >> 6;
    const int ts   = w >> 2;                  // t-set 0/1
    const int p    = w & 3;                   // g-group 0..3
    const int lane = tid & 63;
    const int quad = lane >> 4;
    const int l15  = lane & 15;
    const int t0   = tt * 32;

    float c00, c01, c10, c11;
    {
        const float h = -0.72134752f;         // -0.5*log2(e)
        float ls;
        ls = 1e-5f + softplus_f(lsp[0]); c00 = h / (ls * ls);
        ls = 1e-5f + softplus_f(lsp[1]); c01 = h / (ls * ls);
        ls = 1e-5f + softplus_f(lsp[2]); c10 = h / (ls * ls);
        ls = 1e-5f + softplus_f(lsp[3]); c11 = h / (ls * ls);
    }

    // this wave's 16 t-rows
    const float xt0 = xt[(size_t)(b * NT_ + t0 + ts * 16 + l15) * 2 + 0];
    const float xt1 = xt[(size_t)(b * NT_ + t0 + ts * 16 + l15) * 2 + 1];

    f32x4 acc[2][8];                          // [k][nt] = 64 regs
    #pragma unroll
    for (int k = 0; k < 2; ++k)
        #pragma unroll
        for (int n = 0; n < 8; ++n) acc[k][n] = (f32x4)0.0f;

    unsigned short* const slot0 = lds + p * 8192;   // pair-shared 2 x 8 KB
    unsigned short* const slot1 = slot0 + 4096;
    const float* xgq = xg + (size_t)(b * G_ + p * 1024 + quad * 8) * 2;
    // own staging half: shorts [ts*2048, ts*2048+2048) of each 4096-short chunk
    const unsigned short* zs = Zt + (size_t)(b * 128 + p * 32) * 4096
                               + ts * 2048 + lane * 8;

    #define STAGE(C, TILE) {                                                   \
        const unsigned short* zc = zs + (size_t)(C) * 4096;                    \
        _Pragma("unroll")                                                      \
        for (int i = 0; i < 4; ++i)                                            \
            gl2lds16(zc + i * 512, (TILE) + ts * 2048 + i * 512);              \
    }

    // prologue: xv(0) FIRST (oldest -> its auto-wait leaves stages in flight)
    float4 xv0 = *(const float4*)(xgq + 0);
    float4 xv1 = *(const float4*)(xgq + 4);
    float4 xv2 = *(const float4*)(xgq + 8);
    float4 xv3 = *(const float4*)(xgq + 12);
    STAGE(0, slot0);
    STAGE(1, slot1);

    #define CHUNK_BODY(CH, TILE)                                               \
    {                                                                          \
        const int ch_ = (CH);                                                  \
        float gx[8], gy[8];                                                    \
        gx[0]=xv0.x; gy[0]=xv0.y; gx[1]=xv0.z; gy[1]=xv0.w;                    \
        gx[2]=xv1.x; gy[2]=xv1.y; gx[3]=xv1.z; gy[3]=xv1.w;                    \
        gx[4]=xv2.x; gy[4]=xv2.y; gx[5]=xv2.z; gy[5]=xv2.w;                    \
        gx[6]=xv3.x; gy[6]=xv3.y; gx[7]=xv3.z; gy[7]=xv3.w;                    \
        union { bf16x8 v; unsigned int u[4]; } a0, a1;                         \
        {                                                                      \
            unsigned int w0b[8], w1b[8];                                       \
            _Pragma("unroll")                                                  \
            for (int j = 0; j < 8; ++j) {                                      \
                const float d0 = xt0 - gx[j];                                  \
                const float d1 = xt1 - gy[j];                                  \
                const float q0 = d0 * d0;                                      \
                const float q1 = d1 * d1;                                      \
                const float e0 = fmaf(q1, c10, q0 * c00);                      \
                const float e1 = fmaf(q1, c11, q0 * c01);                      \
                w0b[j] = __float_as_uint(__builtin_amdgcn_exp2f(e0));          \
                w1b[j] = __float_as_uint(__builtin_amdgcn_exp2f(e1));          \
            }                                                                  \
            _Pragma("unroll")                                                  \
            for (int h = 0; h < 4; ++h) {                                      \
                a0.u[h] = __builtin_amdgcn_perm(w0b[2*h+1], w0b[2*h], 0x07060302u); \
                a1.u[h] = __builtin_amdgcn_perm(w1b[2*h+1], w1b[2*h], 0x07060302u); \
            }                                                                  \
        }                                                                      \
        /* counted drain: S(ch) own-half done; S(ch+1)+xv stay in flight */    \
        __builtin_amdgcn_s_waitcnt(0x0F78);          /* vmcnt(8) */            \
        if (ch_ < 31) {                                                        \
            const float* xp = xgq + (ch_ + 1) * 64;                            \
            xv0 = *(const float4*)(xp + 0);                                    \
            xv1 = *(const float4*)(xp + 4);                                    \
            xv2 = *(const float4*)(xp + 8);                                    \
            xv3 = *(const float4*)(xp + 12);                                   \
        }                                                                      \
        __builtin_amdgcn_s_barrier();   /* tile(ch): both halves visible */    \
        _Pragma("unroll")                                                      \
        for (int nt = 0; nt < 8; ++nt) {                                       \
            const bf16x8 bz = *(const bf16x8*)((TILE) + nt * 512 + l15 * 32 + quad * 8); \
            acc[0][nt] = __builtin_amdgcn_mfma_f32_16x16x32_bf16(a0.v, bz, acc[0][nt], 0, 0, 0); \
            acc[1][nt] = __builtin_amdgcn_mfma_f32_16x16x32_bf16(a1.v, bz, acc[1][nt], 0, 0, 0); \
        }                                                                      \
        __builtin_amdgcn_s_waitcnt(0xC07F);          /* lgkmcnt(0) */          \
        __builtin_amdgcn_s_barrier();   /* partner's reads of slot done */     \
        if (ch_ < 30) STAGE(ch_ + 2, TILE);                                    \
    }

    for (int q = 0; q < 16; ++q) {
        CHUNK_BODY(2 * q,     slot0);
        CHUNK_BODY(2 * q + 1, slot1);
    }
    #undef CHUNK_BODY
    #undef STAGE

    // ---- 2-round g-split reduction per t-set (4 waves each, parallel) ----
    float* const red = (float*)lds;           // slot s: 16 KB at s*4096 floats
    #define RED_W(slot) { \
        float* bp = &red[(slot) * 4096 + lane * 4]; \
        _Pragma("unroll") \
        for (int k = 0; k < 2; ++k) \
            _Pragma("unroll") \
            for (int n = 0; n < 8; ++n) \
                *(f32x4*)(bp + (k * 8 + n) * 256) = acc[k][n]; }
    #define RED_A(slot) { \
        const float* bp = &red[(slot) * 4096 + lane * 4]; \
        _Pragma("unroll") \
        for (int k = 0; k < 2; ++k) \
            _Pragma("unroll") \
            for (int n = 0; n < 8; ++n) \
                acc[k][n] += *(const f32x4*)(bp + (k * 8 + n) * 256); }

    __syncthreads();                          // full drain: main loop done
    if (p >= 2) RED_W(ts * 2 + (p - 2));      // ts0:{p2->0,p3->1} ts1:{p2->2,p3->3}
    __syncthreads();
    if (p < 2) RED_A(ts * 2 + p);             // p0+=slot(ts*2), p1+=slot(ts*2+1)
    __syncthreads();                          // protect slot overwrite
    if (p == 1) RED_W(ts);                    // ts0p1->slot0, ts1p1->slot1
    __syncthreads();
    if (p == 0) {
        RED_A(ts);
        const int tr = t0 + ts * 16 + quad * 4;
        #pragma unroll
        for (int nt = 0; nt < 8; ++nt) {
            float* ob = out + (size_t)(b * NT_ + tr) * (DZ_ * 2) + (nt * 16 + l15) * 2;
            #pragma unroll
            for (int r = 0; r < 4; ++r)
                *(float2*)(ob + (size_t)r * (DZ_ * 2)) =
                    make_float2(acc[0][nt][r], acc[1][nt][r]);
        }
    }
    #undef RED_W
    #undef RED_A
}

extern "C" void kernel_launch(void* const* d_in, const int* in_sizes, int n_in,
                              void* d_out, int out_size, void* d_ws, size_t ws_size,
                              hipStream_t stream)
{
    const float* x_grid = (const float*)d_in[0];   // (4,64,64,2)
    const float* z_grid = (const float*)d_in[1];   // (4,64,64,128)
    const float* xt     = (const float*)d_in[2];   // (4,2048,2)
    const float* lsp    = (const float*)d_in[3];   // (2,2)
    float* out = (float*)d_out;                    // (4,2048,256) fp32
    unsigned short* Zt = (unsigned short*)d_ws;    // tiled, 4 MB

    hipLaunchKernelGGL(transpose_z, dim3(512), dim3(256), 0, stream, z_grid, Zt);
    hipLaunchKernelGGL(setconv_main, dim3(256), dim3(512), 0, stream,
                       xt, x_grid, lsp, Zt, out);
}

// Round 5
// 112.405 us; speedup vs baseline: 1.9637x; 1.0184x over previous
//
#include <hip/hip_runtime.h>
#include <hip/hip_bf16.h>
#include <cmath>

#define B_   4
#define NT_  2048
#define G_   4096
#define DZ_  128

typedef __attribute__((ext_vector_type(8))) short bf16x8;
typedef __attribute__((ext_vector_type(4))) float f32x4;

__device__ __forceinline__ float softplus_f(float x) {
    return fmaxf(x, 0.0f) + log1pf(expf(-fabsf(x)));
}

// z_grid (B,G,DZ) fp32 -> Zt2 tiled bf16: Zt2[((b*128 + c)*128 + z)*32 + gi],
// c = g>>5, gi = g&31.  Each 8 KB chunk-tile is contiguous.  (unchanged)
__global__ __launch_bounds__(256, 1)
void transpose_z(const float* __restrict__ z, unsigned short* __restrict__ zt)
{
    __shared__ unsigned short tile[64][66];
    const int bx = blockIdx.x;                // 4b * 64gt * 2zt = 512
    const int zti = bx & 1;
    const int gt  = (bx >> 1) & 63;
    const int b   = bx >> 7;
    const int g0 = gt * 64, z0 = zti * 64;
    const int tid = threadIdx.x;
    const int zl = tid & 63, gl = tid >> 6;
    #pragma unroll
    for (int i = 0; i < 16; ++i) {
        const int g = gl + i * 4;
        const float v = z[(size_t)(b * G_ + g0 + g) * DZ_ + z0 + zl];
        unsigned int u = __float_as_uint(v);
        u = u + 0x7FFFu + ((u >> 16) & 1u);   // RNE to bf16
        tile[g][zl] = (unsigned short)(u >> 16);
    }
    __syncthreads();
    const int gp = (tid & 31) * 2, zi = tid >> 5;
    const int c  = (g0 + gp) >> 5, gi = gp & 31;
    #pragma unroll
    for (int i = 0; i < 8; ++i) {
        const int zz = zi + i * 8;
        const unsigned int lo = tile[gp][zz], hi = tile[gp + 1][zz];
        *(unsigned int*)(zt + ((size_t)(b * 128 + c) * 128 + z0 + zz) * 32 + gi)
            = lo | (hi << 16);
    }
}

// v5b: Block = 512 thr (8 waves), (b, 32 t) x 128 z x 4096 g.
// Waves: w = ts*4 + p.  ts = t-set (16 rows each), p = g-group (1024 g, 32
// chunks of 32 g).  NO LDS STAGING, NO BARRIERS in the main loop: B-frags are
// contiguous 16 B/lane in Zt (the old LDS tile was a verbatim linear copy), so
// load them global->VGPR, register-double-buffered one chunk ahead.  The two
// ts-waves of a p-group read the same Zt lines back-to-back -> L1/L2 hits keep
// the Tt=32 traffic halving.  Compiler inserts counted vmcnt waits from
// register dataflow.  xv (xg coords) reloaded per chunk (L1/L2-resident,
// saves 32 VGPRs of peak pressure vs double-buffering it).
// acc = 64 regs/wave (no-spill regime).  LDS used only for the reduction.
__global__ __launch_bounds__(512, 2)
void setconv_main(const float* __restrict__ xt,
                  const float* __restrict__ xg,
                  const float* __restrict__ lsp,
                  const unsigned short* __restrict__ Zt,
                  float* __restrict__ out)
{
    __shared__ __align__(16) float red[16384];   // 64 KB, reduction only

    const int bx = blockIdx.x;                // 256 blocks = 4b x 64tt
    const int b  = bx & 3;                    // one b per XCD (bx%8 -> XCD)
    const int tt = bx >> 2;                   // 0..63
    const int tid  = threadIdx.x;
    const int w    = tid >> 6;
    const int ts   = w >> 2;                  // t-set 0/1
    const int p    = w & 3;                   // g-group 0..3
    const int lane = tid & 63;
    const int quad = lane >> 4;
    const int l15  = lane & 15;
    const int t0   = tt * 32;

    float c00, c01, c10, c11;
    {
        const float h = -0.72134752f;         // -0.5*log2(e)
        float ls;
        ls = 1e-5f + softplus_f(lsp[0]); c00 = h / (ls * ls);
        ls = 1e-5f + softplus_f(lsp[1]); c01 = h / (ls * ls);
        ls = 1e-5f + softplus_f(lsp[2]); c10 = h / (ls * ls);
        ls = 1e-5f + softplus_f(lsp[3]); c11 = h / (ls * ls);
    }

    // this wave's 16 t-rows
    const float xt0 = xt[(size_t)(b * NT_ + t0 + ts * 16 + l15) * 2 + 0];
    const float xt1 = xt[(size_t)(b * NT_ + t0 + ts * 16 + l15) * 2 + 1];

    f32x4 acc[2][8];                          // [k][nt] = 64 regs (AGPR-able)
    #pragma unroll
    for (int k = 0; k < 2; ++k)
        #pragma unroll
        for (int n = 0; n < 8; ++n) acc[k][n] = (f32x4)0.0f;

    // B-frag base in Zt for this wave: chunk c at +c*4096 shorts, frag nt at
    // +nt*512 shorts; per-lane offset l15*32 + quad*8 shorts (16 B/lane,
    // 64 lanes cover the 1 KB fragment row exactly -> fully coalesced).
    const unsigned short* zb = Zt + (size_t)(b * 128 + p * 32) * 4096
                               + l15 * 32 + quad * 8;
    const float* xgq = xg + (size_t)(b * G_ + p * 1024 + quad * 8) * 2;

    bf16x8 bzA[8], bzB[8];

    // prologue: B(0)
    #pragma unroll
    for (int nt = 0; nt < 8; ++nt)
        bzA[nt] = *(const bf16x8*)(zb + nt * 512);

    #define CHUNK(CH, BZC, BZN)                                                \
    {                                                                          \
        const int ch_ = (CH);                                                  \
        const float* xp = xgq + ch_ * 64;                                      \
        const float4 xv0 = *(const float4*)(xp + 0);                           \
        const float4 xv1 = *(const float4*)(xp + 4);                           \
        const float4 xv2 = *(const float4*)(xp + 8);                           \
        const float4 xv3 = *(const float4*)(xp + 12);                          \
        float gx[8], gy[8];                                                    \
        gx[0]=xv0.x; gy[0]=xv0.y; gx[1]=xv0.z; gy[1]=xv0.w;                    \
        gx[2]=xv1.x; gy[2]=xv1.y; gx[3]=xv1.z; gy[3]=xv1.w;                    \
        gx[4]=xv2.x; gy[4]=xv2.y; gx[5]=xv2.z; gy[5]=xv2.w;                    \
        gx[6]=xv3.x; gy[6]=xv3.y; gx[7]=xv3.z; gy[7]=xv3.w;                    \
        union { bf16x8 v; unsigned int u[4]; } a0, a1;                         \
        {                                                                      \
            unsigned int w0b[8], w1b[8];                                       \
            _Pragma("unroll")                                                  \
            for (int j = 0; j < 8; ++j) {                                      \
                const float d0 = xt0 - gx[j];                                  \
                const float d1 = xt1 - gy[j];                                  \
                const float q0 = d0 * d0;                                      \
                const float q1 = d1 * d1;                                      \
                const float e0 = fmaf(q1, c10, q0 * c00);                      \
                const float e1 = fmaf(q1, c11, q0 * c01);                      \
                w0b[j] = __float_as_uint(__builtin_amdgcn_exp2f(e0));          \
                w1b[j] = __float_as_uint(__builtin_amdgcn_exp2f(e1));          \
            }                                                                  \
            _Pragma("unroll")                                                  \
            for (int h = 0; h < 4; ++h) {                                      \
                a0.u[h] = __builtin_amdgcn_perm(w0b[2*h+1], w0b[2*h], 0x07060302u); \
                a1.u[h] = __builtin_amdgcn_perm(w1b[2*h+1], w1b[2*h], 0x07060302u); \
            }                                                                  \
        }                                                                      \
        /* prefetch B(ch+1) while weights for ch are computed/consumed */      \
        if (ch_ < 31) {                                                        \
            const unsigned short* zc = zb + (size_t)(ch_ + 1) * 4096;          \
            _Pragma("unroll")                                                  \
            for (int nt = 0; nt < 8; ++nt)                                     \
                BZN[nt] = *(const bf16x8*)(zc + nt * 512);                     \
        }                                                                      \
        _Pragma("unroll")                                                      \
        for (int nt = 0; nt < 8; ++nt) {                                       \
            acc[0][nt] = __builtin_amdgcn_mfma_f32_16x16x32_bf16(a0.v, BZC[nt], acc[0][nt], 0, 0, 0); \
            acc[1][nt] = __builtin_amdgcn_mfma_f32_16x16x32_bf16(a1.v, BZC[nt], acc[1][nt], 0, 0, 0); \
        }                                                                      \
    }

    for (int q = 0; q < 16; ++q) {
        CHUNK(2 * q,     bzA, bzB);
        CHUNK(2 * q + 1, bzB, bzA);
    }
    #undef CHUNK

    // ---- 2-round g-split reduction per t-set (4 waves each, parallel) ----
    #define RED_W(slot) { \
        float* bp = &red[(slot) * 4096 + lane * 4]; \
        _Pragma("unroll") \
        for (int k = 0; k < 2; ++k) \
            _Pragma("unroll") \
            for (int n = 0; n < 8; ++n) \
                *(f32x4*)(bp + (k * 8 + n) * 256) = acc[k][n]; }
    #define RED_A(slot) { \
        const float* bp = &red[(slot) * 4096 + lane * 4]; \
        _Pragma("unroll") \
        for (int k = 0; k < 2; ++k) \
            _Pragma("unroll") \
            for (int n = 0; n < 8; ++n) \
                acc[k][n] += *(const f32x4*)(bp + (k * 8 + n) * 256); }

    __syncthreads();
    if (p >= 2) RED_W(ts * 2 + (p - 2));      // ts0:{p2->0,p3->1} ts1:{p2->2,p3->3}
    __syncthreads();
    if (p < 2) RED_A(ts * 2 + p);             // p0+=slot(ts*2), p1+=slot(ts*2+1)
    __syncthreads();                          // protect slot overwrite
    if (p == 1) RED_W(ts);                    // ts0p1->slot0, ts1p1->slot1
    __syncthreads();
    if (p == 0) {
        RED_A(ts);
        const int tr = t0 + ts * 16 + quad * 4;
        #pragma unroll
        for (int nt = 0; nt < 8; ++nt) {
            float* ob = out + (size_t)(b * NT_ + tr) * (DZ_ * 2) + (nt * 16 + l15) * 2;
            #pragma unroll
            for (int r = 0; r < 4; ++r)
                *(float2*)(ob + (size_t)r * (DZ_ * 2)) =
                    make_float2(acc[0][nt][r], acc[1][nt][r]);
        }
    }
    #undef RED_W
    #undef RED_A
}

extern "C" void kernel_launch(void* const* d_in, const int* in_sizes, int n_in,
                              void* d_out, int out_size, void* d_ws, size_t ws_size,
                              hipStream_t stream)
{
    const float* x_grid = (const float*)d_in[0];   // (4,64,64,2)
    const float* z_grid = (const float*)d_in[1];   // (4,64,64,128)
    const float* xt     = (const float*)d_in[2];   // (4,2048,2)
    const float* lsp    = (const float*)d_in[3];   // (2,2)
    float* out = (float*)d_out;                    // (4,2048,256) fp32
    unsigned short* Zt = (unsigned short*)d_ws;    // tiled, 4 MB

    hipLaunchKernelGGL(transpose_z, dim3(512), dim3(256), 0, stream, z_grid, Zt);
    hipLaunchKernelGGL(setconv_main, dim3(256), dim3(512), 0, stream,
                       xt, x_grid, lsp, Zt, out);
}

// Round 6
// 112.295 us; speedup vs baseline: 1.9656x; 1.0010x over previous
//
#include <hip/hip_runtime.h>
#include <hip/hip_bf16.h>
#include <cmath>

#define B_   4
#define NT_  2048
#define G_   4096
#define DZ_  128

typedef __attribute__((ext_vector_type(8))) short bf16x8;
typedef __attribute__((ext_vector_type(4))) float f32x4;

__device__ __forceinline__ float softplus_f(float x) {
    return fmaxf(x, 0.0f) + log1pf(expf(-fabsf(x)));
}

// z_grid (B,G,DZ) fp32 -> Zt2 tiled bf16: Zt2[((b*128 + c)*128 + z)*32 + gi],
// c = g>>5, gi = g&31.  Each 8 KB chunk-tile is contiguous.  (unchanged)
__global__ __launch_bounds__(256, 1)
void transpose_z(const float* __restrict__ z, unsigned short* __restrict__ zt)
{
    __shared__ unsigned short tile[64][66];
    const int bx = blockIdx.x;                // 4b * 64gt * 2zt = 512
    const int zti = bx & 1;
    const int gt  = (bx >> 1) & 63;
    const int b   = bx >> 7;
    const int g0 = gt * 64, z0 = zti * 64;
    const int tid = threadIdx.x;
    const int zl = tid & 63, gl = tid >> 6;
    #pragma unroll
    for (int i = 0; i < 16; ++i) {
        const int g = gl + i * 4;
        const float v = z[(size_t)(b * G_ + g0 + g) * DZ_ + z0 + zl];
        unsigned int u = __float_as_uint(v);
        u = u + 0x7FFFu + ((u >> 16) & 1u);   // RNE to bf16
        tile[g][zl] = (unsigned short)(u >> 16);
    }
    __syncthreads();
    const int gp = (tid & 31) * 2, zi = tid >> 5;
    const int c  = (g0 + gp) >> 5, gi = gp & 31;
    #pragma unroll
    for (int i = 0; i < 8; ++i) {
        const int zz = zi + i * 8;
        const unsigned int lo = tile[gp][zz], hi = tile[gp + 1][zz];
        *(unsigned int*)(zt + ((size_t)(b * 128 + c) * 128 + z0 + zz) * 32 + gi)
            = lo | (hi << 16);
    }
}

// v6: v5b + xv register double-buffer.  Block = 512 thr (8 waves),
// (b, 32 t) x 128 z x 4096 g.  Waves: w = ts*4 + p; ts-pairs share Zt lines
// (L1 hits), no LDS staging, no main-loop barriers.  Per chunk, the issue
// order is: prefetch xv(ch+1) THEN B(ch+1) at the TOP, then weights(ch) from
// registers (waits only to depth >=12, nothing fresh), then MFMA(ch) (its
// B-frags are 12 deep and had a full chunk ~500 cyc to land).  Steady state
// exposes no load latency -- this was v5b's 3000-cyc/chunk stall (xv loaded
// and immediately consumed = vmcnt(0) + L2 latency every chunk).
__global__ __launch_bounds__(512, 2)
void setconv_main(const float* __restrict__ xt,
                  const float* __restrict__ xg,
                  const float* __restrict__ lsp,
                  const unsigned short* __restrict__ Zt,
                  float* __restrict__ out)
{
    __shared__ __align__(16) float red[16384];   // 64 KB, reduction only

    const int bx = blockIdx.x;                // 256 blocks = 4b x 64tt
    const int b  = bx & 3;                    // one b per XCD (bx%8 -> XCD)
    const int tt = bx >> 2;                   // 0..63
    const int tid  = threadIdx.x;
    const int w    = tid >> 6;
    const int ts   = w >> 2;                  // t-set 0/1
    const int p    = w & 3;                   // g-group 0..3
    const int lane = tid & 63;
    const int quad = lane >> 4;
    const int l15  = lane & 15;
    const int t0   = tt * 32;

    float c00, c01, c10, c11;
    {
        const float h = -0.72134752f;         // -0.5*log2(e)
        float ls;
        ls = 1e-5f + softplus_f(lsp[0]); c00 = h / (ls * ls);
        ls = 1e-5f + softplus_f(lsp[1]); c01 = h / (ls * ls);
        ls = 1e-5f + softplus_f(lsp[2]); c10 = h / (ls * ls);
        ls = 1e-5f + softplus_f(lsp[3]); c11 = h / (ls * ls);
    }

    // this wave's 16 t-rows
    const float xt0 = xt[(size_t)(b * NT_ + t0 + ts * 16 + l15) * 2 + 0];
    const float xt1 = xt[(size_t)(b * NT_ + t0 + ts * 16 + l15) * 2 + 1];

    f32x4 acc[2][8];                          // [k][nt] = 64 regs (AGPR-able)
    #pragma unroll
    for (int k = 0; k < 2; ++k)
        #pragma unroll
        for (int n = 0; n < 8; ++n) acc[k][n] = (f32x4)0.0f;

    // B-frag base in Zt for this wave: chunk c at +c*4096 shorts, frag nt at
    // +nt*512 shorts; per-lane offset l15*32 + quad*8 shorts (16 B/lane,
    // 64 lanes cover the 1 KB fragment exactly -> fully coalesced).
    const unsigned short* zb = Zt + (size_t)(b * 128 + p * 32) * 4096
                               + l15 * 32 + quad * 8;
    const float* xgq = xg + (size_t)(b * G_ + p * 1024 + quad * 8) * 2;

    bf16x8 bzA[8], bzB[8];
    float4 xa0, xa1, xa2, xa3, xb0, xb1, xb2, xb3;

    // prologue: xv(0) and B(0)
    xa0 = *(const float4*)(xgq + 0);
    xa1 = *(const float4*)(xgq + 4);
    xa2 = *(const float4*)(xgq + 8);
    xa3 = *(const float4*)(xgq + 12);
    #pragma unroll
    for (int nt = 0; nt < 8; ++nt)
        bzA[nt] = *(const bf16x8*)(zb + nt * 512);

    #define CHUNK(CH, BZC, BZN, XC0, XC1, XC2, XC3, XN0, XN1, XN2, XN3)        \
    {                                                                          \
        const int ch_ = (CH);                                                  \
        /* prefetch chunk ch+1 FIRST: xv then B (so any wait for xv(ch+1)      \
           later still leaves B(ch+1) in flight) */                            \
        if (ch_ < 31) {                                                        \
            const float* xp = xgq + (ch_ + 1) * 64;                            \
            XN0 = *(const float4*)(xp + 0);                                    \
            XN1 = *(const float4*)(xp + 4);                                    \
            XN2 = *(const float4*)(xp + 8);                                    \
            XN3 = *(const float4*)(xp + 12);                                   \
            const unsigned short* zc = zb + (size_t)(ch_ + 1) * 4096;          \
            _Pragma("unroll")                                                  \
            for (int nt = 0; nt < 8; ++nt)                                     \
                BZN[nt] = *(const bf16x8*)(zc + nt * 512);                     \
        }                                                                      \
        float gx[8], gy[8];                                                    \
        gx[0]=XC0.x; gy[0]=XC0.y; gx[1]=XC0.z; gy[1]=XC0.w;                    \
        gx[2]=XC1.x; gy[2]=XC1.y; gx[3]=XC1.z; gy[3]=XC1.w;                    \
        gx[4]=XC2.x; gy[4]=XC2.y; gx[5]=XC2.z; gy[5]=XC2.w;                    \
        gx[6]=XC3.x; gy[6]=XC3.y; gx[7]=XC3.z; gy[7]=XC3.w;                    \
        union { bf16x8 v; unsigned int u[4]; } a0, a1;                         \
        {                                                                      \
            unsigned int w0b[8], w1b[8];                                       \
            _Pragma("unroll")                                                  \
            for (int j = 0; j < 8; ++j) {                                      \
                const float d0 = xt0 - gx[j];                                  \
                const float d1 = xt1 - gy[j];                                  \
                const float q0 = d0 * d0;                                      \
                const float q1 = d1 * d1;                                      \
                const float e0 = fmaf(q1, c10, q0 * c00);                      \
                const float e1 = fmaf(q1, c11, q0 * c01);                      \
                w0b[j] = __float_as_uint(__builtin_amdgcn_exp2f(e0));          \
                w1b[j] = __float_as_uint(__builtin_amdgcn_exp2f(e1));          \
            }                                                                  \
            _Pragma("unroll")                                                  \
            for (int h = 0; h < 4; ++h) {                                      \
                a0.u[h] = __builtin_amdgcn_perm(w0b[2*h+1], w0b[2*h], 0x07060302u); \
                a1.u[h] = __builtin_amdgcn_perm(w1b[2*h+1], w1b[2*h], 0x07060302u); \
            }                                                                  \
        }                                                                      \
        _Pragma("unroll")                                                      \
        for (int nt = 0; nt < 8; ++nt) {                                       \
            acc[0][nt] = __builtin_amdgcn_mfma_f32_16x16x32_bf16(a0.v, BZC[nt], acc[0][nt], 0, 0, 0); \
            acc[1][nt] = __builtin_amdgcn_mfma_f32_16x16x32_bf16(a1.v, BZC[nt], acc[1][nt], 0, 0, 0); \
        }                                                                      \
    }

    for (int q = 0; q < 16; ++q) {
        CHUNK(2 * q,     bzA, bzB, xa0, xa1, xa2, xa3, xb0, xb1, xb2, xb3);
        CHUNK(2 * q + 1, bzB, bzA, xb0, xb1, xb2, xb3, xa0, xa1, xa2, xa3);
    }
    #undef CHUNK

    // ---- 2-round g-split reduction per t-set (4 waves each, parallel) ----
    #define RED_W(slot) { \
        float* bp = &red[(slot) * 4096 + lane * 4]; \
        _Pragma("unroll") \
        for (int k = 0; k < 2; ++k) \
            _Pragma("unroll") \
            for (int n = 0; n < 8; ++n) \
                *(f32x4*)(bp + (k * 8 + n) * 256) = acc[k][n]; }
    #define RED_A(slot) { \
        const float* bp = &red[(slot) * 4096 + lane * 4]; \
        _Pragma("unroll") \
        for (int k = 0; k < 2; ++k) \
            _Pragma("unroll") \
            for (int n = 0; n < 8; ++n) \
                acc[k][n] += *(const f32x4*)(bp + (k * 8 + n) * 256); }

    __syncthreads();
    if (p >= 2) RED_W(ts * 2 + (p - 2));      // ts0:{p2->0,p3->1} ts1:{p2->2,p3->3}
    __syncthreads();
    if (p < 2) RED_A(ts * 2 + p);             // p0+=slot(ts*2), p1+=slot(ts*2+1)
    __syncthreads();                          // protect slot overwrite
    if (p == 1) RED_W(ts);                    // ts0p1->slot0, ts1p1->slot1
    __syncthreads();
    if (p == 0) {
        RED_A(ts);
        const int tr = t0 + ts * 16 + quad * 4;
        #pragma unroll
        for (int nt = 0; nt < 8; ++nt) {
            float* ob = out + (size_t)(b * NT_ + tr) * (DZ_ * 2) + (nt * 16 + l15) * 2;
            #pragma unroll
            for (int r = 0; r < 4; ++r)
                *(float2*)(ob + (size_t)r * (DZ_ * 2)) =
                    make_float2(acc[0][nt][r], acc[1][nt][r]);
        }
    }
    #undef RED_W
    #undef RED_A
}

extern "C" void kernel_launch(void* const* d_in, const int* in_sizes, int n_in,
                              void* d_out, int out_size, void* d_ws, size_t ws_size,
                              hipStream_t stream)
{
    const float* x_grid = (const float*)d_in[0];   // (4,64,64,2)
    const float* z_grid = (const float*)d_in[1];   // (4,64,64,128)
    const float* xt     = (const float*)d_in[2];   // (4,2048,2)
    const float* lsp    = (const float*)d_in[3];   // (2,2)
    float* out = (float*)d_out;                    // (4,2048,256) fp32
    unsigned short* Zt = (unsigned short*)d_ws;    // tiled, 4 MB

    hipLaunchKernelGGL(transpose_z, dim3(512), dim3(256), 0, stream, z_grid, Zt);
    hipLaunchKernelGGL(setconv_main, dim3(256), dim3(512), 0, stream,
                       xt, x_grid, lsp, Zt, out);
}